// Round 7
// baseline (189.213 us; speedup 1.0000x reference)
//
#include <hip/hip_runtime.h>
#include <hip/hip_bf16.h>
#include <stdint.h>

// MutualCrossAttention: B=8, C=64, H=W=64 -> T=4096 tokens. Inputs FP32, output FP32.
// dir A: Q=x1, K=V=x2 ; dir B: Q=x2, K=V=x1 ; out = outA + outB, layout [b][c][t].
// R19 = R18 (frag-packed K/V/Q global layout -> every hot load is a contiguous
// 1KB/instr; no ktile; 1 pacing barrier/j) with the REGISTER LIVE SET CUT to
// restore 2 blocks/CU: R18's ~140 regs/wave (108 VGPR + 32 acc) allowed only
// 3 waves/SIMD -> the 2nd 512-thr block couldn't co-schedule (Occupancy 22%).
// Per-wave dependent chains (MFMA->exp2->pack->write, vmcnt) need TLP to fill.
//   - K ping-pong dropped: single kA set, loadK(j+1) issued right after S(j)
//     consumed it; PV(j)'s 16 MFMAs (~300cy) cover the L2 latency.
//   - V pre-phase prefetch dropped: V loads are in-phase in PV (transient regs).
//     R12/R16 proved in-phase V @ 4 waves/SIMD == prefetched V @ 2 waves/SIMD,
//     and V loads are now coalesced (packed layout), not 16-line scatters.
// Target: ~75 VGPR + 32 acc <= 128 -> 4 waves/SIMD under __launch_bounds__(512,2).
//   kt chunk(tt,mt,ch):  lane(quad,l16) holds K[t=tt*64+mt*16+l16][c=ch*32+quad*8+e]
//   vt chunk(tt,ch2,ct): lane(quad,l16) holds V[c=ct*16+l16][t=tt*64+ch2*32+quad*8+e]
// Q frags are kt chunks at (qt, mt=pair*2+rb, ch).
//   - S^T composition (A=K,B=Q then A=V,B=P^T) proved in R3-R5; P^T C/D layout
//     gives 4 consecutive tokens/lane -> b64 pbuf write, b128 read, stride-72.
//   - lp is one scalar per lane (q = l16 column), butterflied over quads.
//   - O^T epilogue: row=c, col=q -> scalar f32 stores coalesced over l16.
// ws: [0,8MB) kt bf16 frag-packed {x1,x2} PRE-SCALED by sqrt(log2(e)/8);
//     [8MB,16MB) vt bf16 frag-packed {x1,x2} unscaled.

#define TT 4096
#define CC 64
#define NB 8

typedef float f32x4 __attribute__((ext_vector_type(4)));
typedef float f32x4a __attribute__((ext_vector_type(4), may_alias));
typedef short s16x8 __attribute__((ext_vector_type(8)));
typedef unsigned int u32x2a __attribute__((ext_vector_type(2), may_alias));
typedef unsigned int u32x4a __attribute__((ext_vector_type(4), may_alias));
typedef float f32a __attribute__((may_alias));

static __device__ __forceinline__ unsigned fbits(float x) { return __float_as_uint(x); }
static __device__ __forceinline__ ushort bf16of(float v) {
    return (ushort)((fbits(v) + 0x8000u) >> 16);
}
static __device__ __forceinline__ unsigned pack2(float a, float b) {
    return __builtin_amdgcn_perm(fbits(b) + 0x8000u, fbits(a) + 0x8000u, 0x07060302u);
}
static __device__ __forceinline__ s16x8 load_frag(const void* p) {
    u32x4a t = *(const u32x4a*)p;
    return __builtin_bit_cast(s16x8, t);
}

#define SQC1 0.4246609177f  // sqrt(log2(e)/8), applied to kt on both Q and K sides

// grid (TT/64, NB, 2), 256 threads. Reads c-major f32, emits frag-packed bf16.
__global__ void prep_k(const float* __restrict__ x1, const float* __restrict__ x2,
                       ushort* __restrict__ kt, ushort* __restrict__ vt) {
    const int inp = blockIdx.z, b = blockIdx.y, tt = blockIdx.x;
    const float* src = (inp == 0 ? x1 : x2) + (size_t)b * CC * TT;
    const size_t plane = (size_t)TT * CC;
    ushort* kd = kt + (size_t)(inp * NB + b) * plane;
    ushort* vd = vt + (size_t)(inp * NB + b) * plane;
    __shared__ ushort lds[64][72];
    const int tid = threadIdx.x;
    const int c  = tid >> 2;        // 0..63: channel row
    const int tg = tid & 3;         // 16-token group within the 64-token tile
    const float* srow = src + (size_t)c * TT + tt * 64 + tg * 16;
    unsigned hw[8];
#pragma unroll
    for (int i = 0; i < 4; ++i) {
        f32x4a v = *(const f32x4a*)(srow + i * 4);
        hw[2 * i]     = pack2(v[0], v[1]);
        hw[2 * i + 1] = pack2(v[2], v[3]);
#pragma unroll
        for (int k = 0; k < 4; ++k) lds[tg * 16 + i * 4 + k][c] = bf16of(v[k] * SQC1);
    }
    // vt frag-packed (unscaled): thread(c,tg) owns V[c][t_local=tg*16..+16] =
    // chunk(tt, ch2=tg>>1, ct=c>>4), lanes (quad=(tg&1)*2 and +1, l16=c&15).
    {
        ushort* vchunk = vd + (((size_t)tt * 2 + (tg >> 1)) * 4 + (c >> 4)) * 512;
        const int l16v = c & 15;
        const int q0v  = (tg & 1) * 2;
        u32x4a w0 = {hw[0], hw[1], hw[2], hw[3]};
        u32x4a w1 = {hw[4], hw[5], hw[6], hw[7]};
        *(u32x4a*)(vchunk + (size_t)(q0v * 16 + l16v) * 8)       = w0;
        *(u32x4a*)(vchunk + (size_t)((q0v + 1) * 16 + l16v) * 8) = w1;
    }
    __syncthreads();
    // kt frag-packed (scaled, from transposed LDS): tid = mt*64 + quad*16 + l16.
    // chunk(tt, mt, ch): lane holds 8 consecutive c at row t = mt*16 + l16.
    const int mt   = tid >> 6;
    const int quad = (tid >> 4) & 3;
    const int l16  = tid & 15;
    const int t    = mt * 16 + l16;
#pragma unroll
    for (int ch = 0; ch < 2; ++ch) {
        u32x4a w = *(const u32x4a*)&lds[t][ch * 32 + quad * 8];
        *(u32x4a*)(kd + (((size_t)tt * 4 + mt) * 2 + ch) * 512 +
                   (size_t)(quad * 16 + l16) * 8) = w;
    }
}

// grid = 512 blocks (qt 0..63 x b 0..7), 512 threads = 8 waves.
// wave: dir = w&1, pair = (w>>1)&1, ks = w>>2 (2048-token half).
__global__ __launch_bounds__(512, 2)
void attn_fused_k(const ushort* __restrict__ kt, const ushort* __restrict__ vt,
                  float* __restrict__ out) {
    const int b    = blockIdx.x & 7;
    const int qt   = blockIdx.x >> 3;
    const int tid  = threadIdx.x;
    const int wave = tid >> 6;
    const int lane = tid & 63;
    const int quad = lane >> 4;
    const int l16  = lane & 15;
    const int dir  = wave & 1;
    const int pair = (wave >> 1) & 1;
    const int ks   = wave >> 2;
    const int q0   = qt * 64 + pair * 32;

    const size_t plane = (size_t)TT * CC;
    // All hot-loop loads: base + chunk*512 + lane*8 (ushorts) = contiguous 1KB/instr.
    const ushort* Qp = kt + (size_t)((dir == 0 ? 0 : NB) + b) * plane + (size_t)lane * 8;
    const ushort* Kp = kt + (size_t)((dir == 0 ? NB : 0) + b) * plane + (size_t)lane * 8;
    const ushort* Vp = vt + (size_t)((dir == 0 ? NB : 0) + b) * plane + (size_t)lane * 8;

    __shared__ __align__(16) ushort pbuf[8][2][16][72];    // 36.9 KB (q rows, tok cols)
    __shared__ float lpx[8][2][16];                        // 1 KB
    f32a* xbuf = (f32a*)&pbuf[0][0][0][0];                 // 16 KB overlay, post-loop

    // Q b-frags = kt chunks (qt, mt = pair*2 + rb, ch), pre-scaled.
    s16x8 qf[2][2];
#pragma unroll
    for (int rb = 0; rb < 2; ++rb)
#pragma unroll
        for (int ch = 0; ch < 2; ++ch)
            qf[rb][ch] = load_frag(Qp + (((size_t)qt * 4 + pair * 2 + rb) * 2 + ch) * 512);

    f32x4 accO[2][4];  // O^T partial: row=c=quad*4+r (+ct*16), col=q=l16 (+rb*16)
#pragma unroll
    for (int rb = 0; rb < 2; ++rb)
#pragma unroll
        for (int ct = 0; ct < 4; ++ct) accO[rb][ct] = (f32x4){0.f, 0.f, 0.f, 0.f};
    float lp[2] = {0.f, 0.f};

    // K frags: SINGLE named set (R14/R15 lesson: arrays spill; R18 lesson:
    // double-buffer costs 32 live regs -> kills the 2nd block/CU).
    s16x8 kA0, kA1, kA2, kA3, kA4, kA5, kA6, kA7;   // K chunks (mt,ch)

    auto loadK = [&](int j) {
        const ushort* p = Kp + (size_t)(ks * 32 + j) * 4096;
        kA0 = load_frag(p);          kA1 = load_frag(p + 512);
        kA2 = load_frag(p + 1024);   kA3 = load_frag(p + 1536);
        kA4 = load_frag(p + 2048);   kA5 = load_frag(p + 2560);
        kA6 = load_frag(p + 3072);   kA7 = load_frag(p + 3584);
    };

    // One mt-slice of S^T: D[row=tok=quad*4+r (+mt*16)][col=q=l16] -> b64 P write.
    auto SmT = [&](s16x8 kc0, s16x8 kc1, int mt) {
#pragma unroll
        for (int rb = 0; rb < 2; ++rb) {
            f32x4 s = (f32x4){0.f, 0.f, 0.f, 0.f};
            s = __builtin_amdgcn_mfma_f32_16x16x32_bf16(kc0, qf[rb][0], s, 0, 0, 0);
            s = __builtin_amdgcn_mfma_f32_16x16x32_bf16(kc1, qf[rb][1], s, 0, 0, 0);
            float p0 = __builtin_amdgcn_exp2f(s[0]);
            float p1 = __builtin_amdgcn_exp2f(s[1]);
            float p2 = __builtin_amdgcn_exp2f(s[2]);
            float p3 = __builtin_amdgcn_exp2f(s[3]);
            lp[rb] += (p0 + p1) + (p2 + p3);
            u32x2a w;
            w[0] = pack2(p0, p1);
            w[1] = pack2(p2, p3);
            *(u32x2a*)&pbuf[wave][rb][l16][mt * 16 + quad * 4] = w;
        }
    };
    // PV(j): A = V loaded IN-PHASE (transient regs, coalesced 1KB chunks; TLP of
    // 4 waves/SIMD covers the L2 latency) [m=c=l16(+ct*16)][k=tok],
    //        B = P^T [n=q=l16][k=tok] (b128 LDS read).
    auto PVphase = [&](int j) {
        const ushort* p = Vp + (size_t)(ks * 32 + j) * 4096;
        s16x8 v0 = load_frag(p);           s16x8 v1 = load_frag(p + 512);
        s16x8 v2 = load_frag(p + 1024);    s16x8 v3 = load_frag(p + 1536);
        s16x8 v4 = load_frag(p + 2048);    s16x8 v5 = load_frag(p + 2560);
        s16x8 v6 = load_frag(p + 3072);    s16x8 v7 = load_frag(p + 3584);
        s16x8 pf0a = load_frag(&pbuf[wave][0][l16][quad * 8]);
        s16x8 pf1a = load_frag(&pbuf[wave][1][l16][quad * 8]);
        accO[0][0] = __builtin_amdgcn_mfma_f32_16x16x32_bf16(v0, pf0a, accO[0][0], 0, 0, 0);
        accO[1][0] = __builtin_amdgcn_mfma_f32_16x16x32_bf16(v0, pf1a, accO[1][0], 0, 0, 0);
        accO[0][1] = __builtin_amdgcn_mfma_f32_16x16x32_bf16(v1, pf0a, accO[0][1], 0, 0, 0);
        accO[1][1] = __builtin_amdgcn_mfma_f32_16x16x32_bf16(v1, pf1a, accO[1][1], 0, 0, 0);
        accO[0][2] = __builtin_amdgcn_mfma_f32_16x16x32_bf16(v2, pf0a, accO[0][2], 0, 0, 0);
        accO[1][2] = __builtin_amdgcn_mfma_f32_16x16x32_bf16(v2, pf1a, accO[1][2], 0, 0, 0);
        accO[0][3] = __builtin_amdgcn_mfma_f32_16x16x32_bf16(v3, pf0a, accO[0][3], 0, 0, 0);
        accO[1][3] = __builtin_amdgcn_mfma_f32_16x16x32_bf16(v3, pf1a, accO[1][3], 0, 0, 0);
        s16x8 pf0b = load_frag(&pbuf[wave][0][l16][32 + quad * 8]);
        s16x8 pf1b = load_frag(&pbuf[wave][1][l16][32 + quad * 8]);
        accO[0][0] = __builtin_amdgcn_mfma_f32_16x16x32_bf16(v4, pf0b, accO[0][0], 0, 0, 0);
        accO[1][0] = __builtin_amdgcn_mfma_f32_16x16x32_bf16(v4, pf1b, accO[1][0], 0, 0, 0);
        accO[0][1] = __builtin_amdgcn_mfma_f32_16x16x32_bf16(v5, pf0b, accO[0][1], 0, 0, 0);
        accO[1][1] = __builtin_amdgcn_mfma_f32_16x16x32_bf16(v5, pf1b, accO[1][1], 0, 0, 0);
        accO[0][2] = __builtin_amdgcn_mfma_f32_16x16x32_bf16(v6, pf0b, accO[0][2], 0, 0, 0);
        accO[1][2] = __builtin_amdgcn_mfma_f32_16x16x32_bf16(v6, pf1b, accO[1][2], 0, 0, 0);
        accO[0][3] = __builtin_amdgcn_mfma_f32_16x16x32_bf16(v7, pf0b, accO[0][3], 0, 0, 0);
        accO[1][3] = __builtin_amdgcn_mfma_f32_16x16x32_bf16(v7, pf1b, accO[1][3], 0, 0, 0);
    };

    // Per j: [pacing bar] -> S(j) (uses kA) -> issue K(j+1) (covered by PV(j))
    // -> PV(j) (in-phase V). pbuf is wave-private; barrier is pacing/L1-dedupe only.
    loadK(0);
#pragma unroll 1
    for (int j = 0; j < 32; ++j) {
        __syncthreads();                 // pacing: keep pair-waves L1-coherent
        SmT(kA0, kA1, 0); SmT(kA2, kA3, 1); SmT(kA4, kA5, 2); SmT(kA6, kA7, 3);
        if (j < 31) loadK(j + 1);        // WAR-safe: S(j) already consumed kA
        PVphase(j);
    }

    // Denominator: quads hold disjoint token subsets for col q=l16.
    float inv[2];
#pragma unroll
    for (int rb = 0; rb < 2; ++rb) {
        float l = lp[rb];
        l += __shfl_xor(l, 16);
        l += __shfl_xor(l, 32);
        lp[rb] = l;
        if (lane < 16) lpx[wave][rb][l16] = l;
    }
    __syncthreads();  // all waves done with pbuf -> xbuf overlay safe; lpx visible
#pragma unroll
    for (int rb = 0; rb < 2; ++rb)
        inv[rb] = __builtin_amdgcn_rcpf(lp[rb] + lpx[wave ^ 4][rb][l16]);

    // 4-phase merge over g = (ks,dir) into xbuf[pair]; g==0 stores.
    const int g = (ks << 1) | dir;
#pragma unroll 1
    for (int ph = 3; ph >= 1; --ph) {
        if (g == ph) {
#pragma unroll
            for (int rb = 0; rb < 2; ++rb)
#pragma unroll
                for (int ct = 0; ct < 4; ++ct)
#pragma unroll
                    for (int r = 0; r < 4; ++r) {
                        const int slot = (pair * 32 + rb * 16 + ct * 4 + r) * 64 + lane;
                        float v = accO[rb][ct][r] * inv[rb];
                        if (ph == 3) xbuf[slot] = v;
                        else xbuf[slot] += v;
                    }
        }
        __syncthreads();
    }
    if (g == 0) {
        float* ob = out + (size_t)b * plane;
#pragma unroll
        for (int rb = 0; rb < 2; ++rb)
#pragma unroll
            for (int ct = 0; ct < 4; ++ct)
#pragma unroll
                for (int r = 0; r < 4; ++r) {
                    float v = accO[rb][ct][r] * inv[rb] +
                              xbuf[(pair * 32 + rb * 16 + ct * 4 + r) * 64 + lane];
                    // out[c = ct*16+quad*4+r][t = q0+rb*16+l16]: coalesced over l16
                    ob[(size_t)(ct * 16 + quad * 4 + r) * TT + q0 + rb * 16 + l16] = v;
                }
    }
}

extern "C" void kernel_launch(void* const* d_in, const int* in_sizes, int n_in,
                              void* d_out, int out_size, void* d_ws, size_t ws_size,
                              hipStream_t stream) {
    const float* x1 = (const float*)d_in[0];
    const float* x2 = (const float*)d_in[1];
    ushort* kt = (ushort*)d_ws;                              // 8 MB frag-packed K/Q
    ushort* vt = (ushort*)d_ws + (size_t)2 * NB * TT * CC;   // 8 MB frag-packed V

    hipLaunchKernelGGL(prep_k, dim3(TT / 64, NB, 2), dim3(256), 0, stream, x1, x2, kt, vt);
    hipLaunchKernelGGL(attn_fused_k, dim3(64 * NB), dim3(512), 0, stream,
                       kt, vt, (float*)d_out);
}